// Round 9
// baseline (105.804 us; speedup 1.0000x reference)
//
#include <hip/hip_runtime.h>

#define HH 256
#define WW 256
#define BB 4
#define HW (HH*WW)
#define N_ITER 20
#define EPSV 1e-8f

#define FUSE 4
#define TILE 32
#define HALO (2*FUSE)            // 8
#define EXT  (TILE + 2*HALO)     // 48
#define EPAD 49                  // odd row stride (in float2 units)
#define NTHR 1024                // 16 waves/CU at 1 block/CU
#define NPX  3                   // ceil(48*48 / 1024)

__device__ __forceinline__ float ldz(const float* __restrict__ p, int y, int x) {
    if ((unsigned)y < HH && (unsigned)x < WW) return p[y*WW + x];
    return 0.0f;
}
__device__ __forceinline__ float sobelXg(const float* __restrict__ p, int y, int x) {
    return -ldz(p,y-1,x-1) + ldz(p,y-1,x+1)
         - 2.0f*ldz(p,y,x-1) + 2.0f*ldz(p,y,x+1)
         - ldz(p,y+1,x-1) + ldz(p,y+1,x+1);
}
__device__ __forceinline__ float sobelYg(const float* __restrict__ p, int y, int x) {
    return -ldz(p,y-1,x-1) - 2.0f*ldz(p,y-1,x) - ldz(p,y-1,x+1)
          + ldz(p,y+1,x-1) + 2.0f*ldz(p,y+1,x) + ldz(p,y+1,x+1);
}

__global__ void tvl1_init(const float* __restrict__ xin, float* __restrict__ u,
                          float* __restrict__ p1, float* __restrict__ p2,
                          float* __restrict__ gx, float* __restrict__ gy,
                          float* __restrict__ rc) {
    int x = blockIdx.x*blockDim.x + threadIdx.x;
    int y = blockIdx.y*blockDim.y + threadIdx.y;
    int b = blockIdx.z;
    int idx = y*WW + x;
    int pb = b*2*HW;
    const float* im1 = xin + pb + HW;     // channel 1
    float i1 = im1[idx];
    rc[b*HW + idx] = i1 - xin[pb + idx];  // im1 - im0
    gx[b*HW + idx] = sobelXg(im1, y, x);
    gy[b*HW + idx] = sobelYg(im1, y, x);
    u[pb + idx] = 0.0f;  u[pb + HW + idx] = 0.0f;
    p1[pb + idx] = 0.0f; p1[pb + HW + idx] = 0.0f;
    p2[pb + idx] = 0.0f; p2[pb + HW + idx] = 0.0f;
}

template<int LAST>
__global__ __launch_bounds__(NTHR)
void tvl1_fused(float* __restrict__ u,
                float* __restrict__ p1, float* __restrict__ p2,
                const float* __restrict__ gxc, const float* __restrict__ gyc,
                const float* __restrict__ rcc,
                const float* __restrict__ lam, const float* __restrict__ tau,
                const float* __restrict__ the) {
    // Channel-interleaved LDS: one ds_read_b64 serves both flow channels.
    // 3 fields * 48*49*8B = 55.1 KB.
    __shared__ float2 su [EXT][EPAD];   // (u0,  u1)
    __shared__ float2 sp1[EXT][EPAD];   // (p1c0,p1c1)
    __shared__ float2 sp2[EXT][EPAD];   // (p2c0,p2c1)

    const int tid = threadIdx.x;
    const int b  = blockIdx.z;
    const int ox = blockIdx.x*TILE - HALO;
    const int oy = blockIdx.y*TILE - HALO;
    const int pb = b*2*HW, cb = b*HW;
    const float theta = the[0];
    const float tl = theta * lam[0];
    const float r = tau[0] / theta;

    // ---- static slot <-> pixel mapping ----
    int lys[NPX], lxs[NPX];
    bool act[NPX], upd[NPX];
    #pragma unroll
    for (int k = 0; k < NPX; ++k) {
        int i = tid + k*NTHR;
        bool slot = (i < EXT*EXT);
        int ii = slot ? i : 0;
        int ly = ii / EXT, lx = ii - ly*EXT;
        lys[k] = ly; lxs[k] = lx;
        bool img = ((unsigned)(oy+ly) < HH) && ((unsigned)(ox+lx) < WW);
        // update set: in-image (SAME-pad zeros stay zero) and stencil-readable.
        // No ring shrinking: stale ring-h values are never read by any pixel
        // that remains valid (1 ring per half-step, halo = 8 = #half-steps).
        upd[k] = slot && img &&
                 (ly >= 1) && (ly < EXT-1) && (lx >= 1) && (lx < EXT-1);
        act[k] = slot && img;
    }

    // ---- per-slot register state (planar scalars) ----
    float ru0[NPX], ru1[NPX], rp10[NPX], rp11[NPX], rp20[NPX], rp21[NPX];
    float rgx[NPX], rgy[NPX], rrc[NPX];

    // ---- stage: regs hold pointwise state; LDS gets neighbor-visible copies ----
    #pragma unroll
    for (int k = 0; k < NPX; ++k) {
        int ly = lys[k], lx = lxs[k];
        int gi = (oy+ly)*WW + (ox+lx);
        float v0=0.f, v1=0.f, w0=0.f, w1=0.f, w2=0.f, w3=0.f, a=0.f, c=0.f, d=0.f;
        if (act[k]) {
            v0 = u[pb + gi];       v1 = u[pb + HW + gi];
            w0 = p1[pb + gi];      w1 = p1[pb + HW + gi];
            w2 = p2[pb + gi];      w3 = p2[pb + HW + gi];
            a  = gxc[cb + gi];     c  = gyc[cb + gi];     d = rcc[cb + gi];
        }
        ru0[k]=v0; ru1[k]=v1; rp10[k]=w0; rp11[k]=w1; rp20[k]=w2; rp21[k]=w3;
        rgx[k]=a; rgy[k]=c; rrc[k]=d;
        if (k < 2 || tid < EXT*EXT - 2*NTHR) {   // every slot with i < EXT*EXT
            su [ly][lx] = make_float2(v0, v1);
            sp1[ly][lx] = make_float2(w0, w1);
            sp2[ly][lx] = make_float2(w2, w3);
        }
    }
    __syncthreads();

    #pragma unroll
    for (int it = 0; it < FUSE; ++it) {
        // ---- u half-step: pointwise from regs, p taps from LDS (12 b64 reads) ----
        #pragma unroll
        for (int k = 0; k < NPX; ++k) {
            if (upd[k]) {
                int ly = lys[k], lx = lxs[k];
                // SBX(sp1): 6 taps, cols lx+-1, both channels per read
                float2 a1 = sp1[ly-1][lx-1], b1 = sp1[ly-1][lx+1];
                float2 c1 = sp1[ly  ][lx-1], d1 = sp1[ly  ][lx+1];
                float2 e1 = sp1[ly+1][lx-1], f1 = sp1[ly+1][lx+1];
                float x0 = (b1.x-a1.x) + 2.f*(d1.x-c1.x) + (f1.x-e1.x);
                float x1 = (b1.y-a1.y) + 2.f*(d1.y-c1.y) + (f1.y-e1.y);
                // SBY(sp2): 6 taps, rows ly+-1
                float2 a2 = sp2[ly-1][lx-1], b2 = sp2[ly-1][lx], c2 = sp2[ly-1][lx+1];
                float2 d2 = sp2[ly+1][lx-1], e2 = sp2[ly+1][lx], f2 = sp2[ly+1][lx+1];
                float y0 = (d2.x-a2.x) + 2.f*(e2.x-b2.x) + (f2.x-c2.x);
                float y1 = (d2.y-a2.y) + 2.f*(e2.y-b2.y) + (f2.y-c2.y);

                float g_x = rgx[k], g_y = rgy[k];
                float ng  = g_x*g_x + g_y*g_y + EPSV;
                float rho = rrc[k] + g_x*ru0[k] + g_y*ru1[k];
                float th  = tl * ng;
                float sgn = (rho > 0.f) ? 1.f : ((rho < 0.f) ? -1.f : 0.f);
                float dd  = (fabsf(rho) < th) ? (rho / ng) : (tl * sgn);
                ru0[k] = ru0[k] - dd*g_x + theta*(x0 + y0);
                ru1[k] = ru1[k] - dd*g_y + theta*(x1 + y1);
                su[ly][lx] = make_float2(ru0[k], ru1[k]);
            }
        }
        __syncthreads();

        if (LAST && it == FUSE-1) break;    // 20th p-update never feeds the output

        // ---- p half-step: pointwise from regs, u taps from LDS (8 b64 reads) ----
        #pragma unroll
        for (int k = 0; k < NPX; ++k) {
            if (upd[k]) {
                int ly = lys[k], lx = lxs[k];
                float2 A = su[ly-1][lx-1], B = su[ly-1][lx], C = su[ly-1][lx+1];
                float2 D = su[ly  ][lx-1],                    E = su[ly  ][lx+1];
                float2 F = su[ly+1][lx-1], G = su[ly+1][lx], H = su[ly+1][lx+1];
                float g1x = (C.x-A.x) + 2.f*(E.x-D.x) + (H.x-F.x);
                float g1y = (F.x-A.x) + 2.f*(G.x-B.x) + (H.x-C.x);
                float g2x = (C.y-A.y) + 2.f*(E.y-D.y) + (H.y-F.y);
                float g2y = (F.y-A.y) + 2.f*(G.y-B.y) + (H.y-C.y);
                float inv1 = 1.f / (1.f + r*(fabsf(g1x) + fabsf(g1y)));
                float inv2 = 1.f / (1.f + r*(fabsf(g2x) + fabsf(g2y)));
                rp10[k] = (rp10[k] + r*g1x) * inv1;
                rp11[k] = (rp11[k] + r*g1y) * inv1;
                rp20[k] = (rp20[k] + r*g2x) * inv2;
                rp21[k] = (rp21[k] + r*g2y) * inv2;
                sp1[ly][lx] = make_float2(rp10[k], rp11[k]);
                sp2[ly][lx] = make_float2(rp20[k], rp21[k]);
            }
        }
        __syncthreads();
    }

    // ---- write back interior straight from registers ----
    #pragma unroll
    for (int k = 0; k < NPX; ++k) {
        int ly = lys[k], lx = lxs[k];
        if (upd[k] && ly >= HALO && ly < HALO+TILE && lx >= HALO && lx < HALO+TILE) {
            int go = (oy + ly)*WW + (ox + lx);
            u[pb + go]      = ru0[k];
            u[pb + HW + go] = ru1[k];
            if (!LAST) {
                p1[pb + go]      = rp10[k];
                p1[pb + HW + go] = rp11[k];
                p2[pb + go]      = rp20[k];
                p2[pb + HW + go] = rp21[k];
            }
        }
    }
}

extern "C" void kernel_launch(void* const* d_in, const int* in_sizes, int n_in,
                              void* d_out, int out_size, void* d_ws, size_t ws_size,
                              hipStream_t stream) {
    const float* xin = (const float*)d_in[0];
    const float* lam = (const float*)d_in[1];
    const float* tau = (const float*)d_in[2];
    const float* the = (const float*)d_in[3];
    float* u = (float*)d_out;              // u lives in d_out (B,2,H,W)

    float* ws = (float*)d_ws;
    float* p1 = ws;                        // B*2*HW
    float* p2 = ws + (size_t)BB*2*HW;      // B*2*HW
    float* gx = ws + (size_t)2*BB*2*HW;    // B*HW
    float* gy = gx + (size_t)BB*HW;        // B*HW
    float* rc = gy + (size_t)BB*HW;        // B*HW

    {
        dim3 blk(64, 4, 1);
        dim3 grd(WW/64, HH/4, BB);
        tvl1_init<<<grd, blk, 0, stream>>>(xin, u, p1, p2, gx, gy, rc);
    }

    dim3 blk(NTHR, 1, 1);
    dim3 grd(WW/TILE, HH/TILE, BB);        // 8 x 8 x 4 = 256 blocks = 1/CU
    const int NLAUNCH = N_ITER / FUSE;     // 5
    for (int j = 0; j < NLAUNCH; ++j) {
        if (j < NLAUNCH - 1)
            tvl1_fused<0><<<grd, blk, 0, stream>>>(u, p1, p2, gx, gy, rc, lam, tau, the);
        else
            tvl1_fused<1><<<grd, blk, 0, stream>>>(u, p1, p2, gx, gy, rc, lam, tau, the);
    }
}

// Round 11
// 104.778 us; speedup vs baseline: 1.0098x; 1.0098x over previous
//
#include <hip/hip_runtime.h>

#define HH 256
#define WW 256
#define BB 4
#define HW (HH*WW)
#define N_ITER 20
#define EPSV 1e-8f

#define FUSE 4
#define TILE 32
#define HALO (2*FUSE)            // 8
#define EXT  (TILE + 2*HALO)     // 48
#define EPAD 49                  // odd row stride (in float4 cells)
#define NTHR 1024                // 16 waves/CU at 1 block/CU
#define NPX  3                   // ceil(48*48 / 1024)

__device__ __forceinline__ float ldz(const float* __restrict__ p, int y, int x) {
    if ((unsigned)y < HH && (unsigned)x < WW) return p[y*WW + x];
    return 0.0f;
}
__device__ __forceinline__ float sobelXg(const float* __restrict__ p, int y, int x) {
    return -ldz(p,y-1,x-1) + ldz(p,y-1,x+1)
         - 2.0f*ldz(p,y,x-1) + 2.0f*ldz(p,y,x+1)
         - ldz(p,y+1,x-1) + ldz(p,y+1,x+1);
}
__device__ __forceinline__ float sobelYg(const float* __restrict__ p, int y, int x) {
    return -ldz(p,y-1,x-1) - 2.0f*ldz(p,y-1,x) - ldz(p,y-1,x+1)
          + ldz(p,y+1,x-1) + 2.0f*ldz(p,y+1,x) + ldz(p,y+1,x+1);
}

__global__ void tvl1_init(const float* __restrict__ xin, float* __restrict__ u,
                          float* __restrict__ p1, float* __restrict__ p2,
                          float* __restrict__ gx, float* __restrict__ gy,
                          float* __restrict__ rc) {
    int x = blockIdx.x*blockDim.x + threadIdx.x;
    int y = blockIdx.y*blockDim.y + threadIdx.y;
    int b = blockIdx.z;
    int idx = y*WW + x;
    int pb = b*2*HW;
    const float* im1 = xin + pb + HW;     // channel 1
    float i1 = im1[idx];
    rc[b*HW + idx] = i1 - xin[pb + idx];  // im1 - im0
    gx[b*HW + idx] = sobelXg(im1, y, x);
    gy[b*HW + idx] = sobelYg(im1, y, x);
    u[pb + idx] = 0.0f;  u[pb + HW + idx] = 0.0f;
    p1[pb + idx] = 0.0f; p1[pb + HW + idx] = 0.0f;
    p2[pb + idx] = 0.0f; p2[pb + HW + idx] = 0.0f;
}

template<int LAST>
__global__ __launch_bounds__(NTHR)
void tvl1_fused(float* __restrict__ u,
                float* __restrict__ p1, float* __restrict__ p2,
                const float* __restrict__ gxc, const float* __restrict__ gyc,
                const float* __restrict__ rcc,
                const float* __restrict__ lam, const float* __restrict__ tau,
                const float* __restrict__ the) {
    // All-b128 LDS layout (b64 empirically unsafe on this kernel: R6/R10).
    // sp cell = (p1c0, p1c1, p2c0, p2c1); su cell = (u0, u1, 0, 0).
    // One ds_read_b128 per ring tap serves every field both phases need.
    // 2 planes * 48*49*16B = 73.5 KB.
    __shared__ float4 su [EXT][EPAD];
    __shared__ float4 sp [EXT][EPAD];

    const int tid = threadIdx.x;
    const int b  = blockIdx.z;
    const int ox = blockIdx.x*TILE - HALO;
    const int oy = blockIdx.y*TILE - HALO;
    const int pb = b*2*HW, cb = b*HW;
    const float theta = the[0];
    const float tl = theta * lam[0];
    const float r = tau[0] / theta;

    // ---- static slot <-> pixel mapping ----
    int lys[NPX], lxs[NPX];
    bool act[NPX], upd[NPX];
    #pragma unroll
    for (int k = 0; k < NPX; ++k) {
        int i = tid + k*NTHR;
        bool slot = (i < EXT*EXT);
        int ii = slot ? i : 0;
        int ly = ii / EXT, lx = ii - ly*EXT;
        lys[k] = ly; lxs[k] = lx;
        bool img = ((unsigned)(oy+ly) < HH) && ((unsigned)(ox+lx) < WW);
        // update set: in-image (SAME-pad zeros stay zero) and stencil-readable.
        // No ring shrinking: stale ring-h values are never read by any pixel
        // that remains valid (1 ring per half-step, halo = 8 = #half-steps).
        upd[k] = slot && img &&
                 (ly >= 1) && (ly < EXT-1) && (lx >= 1) && (lx < EXT-1);
        act[k] = slot && img;
    }

    // ---- per-slot register state (planar scalars) ----
    float ru0[NPX], ru1[NPX], rp10[NPX], rp11[NPX], rp20[NPX], rp21[NPX];
    float rgx[NPX], rgy[NPX], rrc[NPX];

    // ---- stage: regs hold pointwise state; LDS gets neighbor-visible copies ----
    #pragma unroll
    for (int k = 0; k < NPX; ++k) {
        int ly = lys[k], lx = lxs[k];
        int gi = (oy+ly)*WW + (ox+lx);
        float v0=0.f, v1=0.f, w0=0.f, w1=0.f, w2=0.f, w3=0.f, a=0.f, c=0.f, d=0.f;
        if (act[k]) {
            v0 = u[pb + gi];       v1 = u[pb + HW + gi];
            w0 = p1[pb + gi];      w1 = p1[pb + HW + gi];
            w2 = p2[pb + gi];      w3 = p2[pb + HW + gi];
            a  = gxc[cb + gi];     c  = gyc[cb + gi];     d = rcc[cb + gi];
        }
        ru0[k]=v0; ru1[k]=v1; rp10[k]=w0; rp11[k]=w1; rp20[k]=w2; rp21[k]=w3;
        rgx[k]=a; rgy[k]=c; rrc[k]=d;
        if (k < 2 || tid < EXT*EXT - 2*NTHR) {   // every slot with i < EXT*EXT
            su[ly][lx] = make_float4(v0, v1, 0.f, 0.f);
            sp[ly][lx] = make_float4(w0, w1, w2, w3);
        }
    }
    __syncthreads();

    #pragma unroll
    for (int it = 0; it < FUSE; ++it) {
        // ---- u half-step: pointwise from regs, p ring from LDS (8 b128 reads) ----
        #pragma unroll
        for (int k = 0; k < NPX; ++k) {
            if (upd[k]) {
                int ly = lys[k], lx = lxs[k];
                float4 A = sp[ly-1][lx-1], B = sp[ly-1][lx], C = sp[ly-1][lx+1];
                float4 D = sp[ly  ][lx-1],                    E = sp[ly  ][lx+1];
                float4 F = sp[ly+1][lx-1], G = sp[ly+1][lx], H = sp[ly+1][lx+1];
                // SBX over p1 (components .x,.y), SBY over p2 (components .z,.w)
                float x0 = (C.x-A.x) + 2.f*(E.x-D.x) + (H.x-F.x);
                float x1 = (C.y-A.y) + 2.f*(E.y-D.y) + (H.y-F.y);
                float y0 = (F.z-A.z) + 2.f*(G.z-B.z) + (H.z-C.z);
                float y1 = (F.w-A.w) + 2.f*(G.w-B.w) + (H.w-C.w);

                float g_x = rgx[k], g_y = rgy[k];
                float ng  = g_x*g_x + g_y*g_y + EPSV;
                float rho = rrc[k] + g_x*ru0[k] + g_y*ru1[k];
                float th  = tl * ng;
                float sgn = (rho > 0.f) ? 1.f : ((rho < 0.f) ? -1.f : 0.f);
                float dd  = (fabsf(rho) < th) ? (rho / ng) : (tl * sgn);
                ru0[k] = ru0[k] - dd*g_x + theta*(x0 + y0);
                ru1[k] = ru1[k] - dd*g_y + theta*(x1 + y1);
                su[ly][lx] = make_float4(ru0[k], ru1[k], 0.f, 0.f);
            }
        }
        __syncthreads();

        if (LAST && it == FUSE-1) break;    // 20th p-update never feeds the output

        // ---- p half-step: pointwise from regs, u ring from LDS (8 b128 reads) ----
        #pragma unroll
        for (int k = 0; k < NPX; ++k) {
            if (upd[k]) {
                int ly = lys[k], lx = lxs[k];
                float4 A = su[ly-1][lx-1], B = su[ly-1][lx], C = su[ly-1][lx+1];
                float4 D = su[ly  ][lx-1],                    E = su[ly  ][lx+1];
                float4 F = su[ly+1][lx-1], G = su[ly+1][lx], H = su[ly+1][lx+1];
                float g1x = (C.x-A.x) + 2.f*(E.x-D.x) + (H.x-F.x);
                float g1y = (F.x-A.x) + 2.f*(G.x-B.x) + (H.x-C.x);
                float g2x = (C.y-A.y) + 2.f*(E.y-D.y) + (H.y-F.y);
                float g2y = (F.y-A.y) + 2.f*(G.y-B.y) + (H.y-C.y);
                float inv1 = 1.f / (1.f + r*(fabsf(g1x) + fabsf(g1y)));
                float inv2 = 1.f / (1.f + r*(fabsf(g2x) + fabsf(g2y)));
                rp10[k] = (rp10[k] + r*g1x) * inv1;
                rp11[k] = (rp11[k] + r*g1y) * inv1;
                rp20[k] = (rp20[k] + r*g2x) * inv2;
                rp21[k] = (rp21[k] + r*g2y) * inv2;
                sp[ly][lx] = make_float4(rp10[k], rp11[k], rp20[k], rp21[k]);
            }
        }
        __syncthreads();
    }

    // ---- write back interior straight from registers ----
    #pragma unroll
    for (int k = 0; k < NPX; ++k) {
        int ly = lys[k], lx = lxs[k];
        if (upd[k] && ly >= HALO && ly < HALO+TILE && lx >= HALO && lx < HALO+TILE) {
            int go = (oy + ly)*WW + (ox + lx);
            u[pb + go]      = ru0[k];
            u[pb + HW + go] = ru1[k];
            if (!LAST) {
                p1[pb + go]      = rp10[k];
                p1[pb + HW + go] = rp11[k];
                p2[pb + go]      = rp20[k];
                p2[pb + HW + go] = rp21[k];
            }
        }
    }
}

extern "C" void kernel_launch(void* const* d_in, const int* in_sizes, int n_in,
                              void* d_out, int out_size, void* d_ws, size_t ws_size,
                              hipStream_t stream) {
    const float* xin = (const float*)d_in[0];
    const float* lam = (const float*)d_in[1];
    const float* tau = (const float*)d_in[2];
    const float* the = (const float*)d_in[3];
    float* u = (float*)d_out;              // u lives in d_out (B,2,H,W)

    float* ws = (float*)d_ws;
    float* p1 = ws;                        // B*2*HW
    float* p2 = ws + (size_t)BB*2*HW;      // B*2*HW
    float* gx = ws + (size_t)2*BB*2*HW;    // B*HW
    float* gy = gx + (size_t)BB*HW;        // B*HW
    float* rc = gy + (size_t)BB*HW;        // B*HW

    {
        dim3 blk(64, 4, 1);
        dim3 grd(WW/64, HH/4, BB);
        tvl1_init<<<grd, blk, 0, stream>>>(xin, u, p1, p2, gx, gy, rc);
    }

    dim3 blk(NTHR, 1, 1);
    dim3 grd(WW/TILE, HH/TILE, BB);        // 8 x 8 x 4 = 256 blocks = 1/CU
    const int NLAUNCH = N_ITER / FUSE;     // 5
    for (int j = 0; j < NLAUNCH; ++j) {
        if (j < NLAUNCH - 1)
            tvl1_fused<0><<<grd, blk, 0, stream>>>(u, p1, p2, gx, gy, rc, lam, tau, the);
        else
            tvl1_fused<1><<<grd, blk, 0, stream>>>(u, p1, p2, gx, gy, rc, lam, tau, the);
    }
}

// Round 12
// 99.394 us; speedup vs baseline: 1.0645x; 1.0542x over previous
//
#include <hip/hip_runtime.h>

#define HH 256
#define WW 256
#define BB 4
#define HW (HH*WW)
#define N_ITER 20
#define EPSV 1e-8f

#define FUSE 4
#define TILE 32
#define HALO (2*FUSE)            // 8
#define EXT  (TILE + 2*HALO)     // 48
#define EPAD 49                  // odd row stride in float4 cells
#define NTHR 768                 // 16 strips of 3 rows x 48 cols
#define RPS  3                   // rows per strip

__device__ __forceinline__ float ldz(const float* __restrict__ p, int y, int x) {
    if ((unsigned)y < HH && (unsigned)x < WW) return p[y*WW + x];
    return 0.0f;
}
__device__ __forceinline__ float sobelXg(const float* __restrict__ p, int y, int x) {
    return -ldz(p,y-1,x-1) + ldz(p,y-1,x+1)
         - 2.0f*ldz(p,y,x-1) + 2.0f*ldz(p,y,x+1)
         - ldz(p,y+1,x-1) + ldz(p,y+1,x+1);
}
__device__ __forceinline__ float sobelYg(const float* __restrict__ p, int y, int x) {
    return -ldz(p,y-1,x-1) - 2.0f*ldz(p,y-1,x) - ldz(p,y-1,x+1)
          + ldz(p,y+1,x-1) + 2.0f*ldz(p,y+1,x) + ldz(p,y+1,x+1);
}

__global__ void tvl1_init(const float* __restrict__ xin, float* __restrict__ u,
                          float* __restrict__ p1, float* __restrict__ p2,
                          float* __restrict__ gx, float* __restrict__ gy,
                          float* __restrict__ rc) {
    int x = blockIdx.x*blockDim.x + threadIdx.x;
    int y = blockIdx.y*blockDim.y + threadIdx.y;
    int b = blockIdx.z;
    int idx = y*WW + x;
    int pb = b*2*HW;
    const float* im1 = xin + pb + HW;     // channel 1
    float i1 = im1[idx];
    rc[b*HW + idx] = i1 - xin[pb + idx];  // im1 - im0
    gx[b*HW + idx] = sobelXg(im1, y, x);
    gy[b*HW + idx] = sobelYg(im1, y, x);
    u[pb + idx] = 0.0f;  u[pb + HW + idx] = 0.0f;
    p1[pb + idx] = 0.0f; p1[pb + HW + idx] = 0.0f;
    p2[pb + idx] = 0.0f; p2[pb + HW + idx] = 0.0f;
}

template<int LAST>
__global__ __launch_bounds__(NTHR)
void tvl1_fused(float* __restrict__ u,
                float* __restrict__ p1, float* __restrict__ p2,
                const float* __restrict__ gxc, const float* __restrict__ gyc,
                const float* __restrict__ rcc,
                const float* __restrict__ lam, const float* __restrict__ tau,
                const float* __restrict__ the) {
    // All-b128 LDS (b64 empirically unsafe: R6/R10).
    // sp cell = (p1c0,p1c1,p2c0,p2c1); su cell = (u0,u1,0,0).
    // Each thread owns a 3-row column strip: own-column cells live in regs;
    // one 5-row x 3-col window (12 LDS reads) serves all 3 pixels per phase.
    __shared__ float4 su[EXT][EPAD];
    __shared__ float4 sp[EXT][EPAD];     // 2 * 48*49*16B = 75.3 KB

    const int tid = threadIdx.x;
    const int sx  = tid % EXT;               // column 0..47 (const divisor)
    const int sy3 = (tid / EXT) * RPS;       // strip top row: 0,3,...,45
    const int b  = blockIdx.z;
    const int ox = blockIdx.x*TILE - HALO;
    const int oy = blockIdx.y*TILE - HALO;
    const int pb = b*2*HW, cb = b*HW;
    const float theta = the[0];
    const float tl = theta * lam[0];
    const float r = tau[0] / theta;

    const int gxx = ox + sx;
    const bool inx = ((unsigned)gxx < WW);

    float ru0[RPS], ru1[RPS], rp10[RPS], rp11[RPS], rp20[RPS], rp21[RPS];
    float rgx[RPS], rgy[RPS], rrc[RPS];
    bool updr[RPS];

    // ---- stage: regs hold the strip's state; LDS gets neighbor-visible copies ----
    #pragma unroll
    for (int j = 0; j < RPS; ++j) {
        int ry = sy3 + j;
        int gyy = oy + ry;
        bool img = inx && ((unsigned)gyy < HH);
        // update set: in-image (SAME-pad zeros stay zero) + stencil-readable.
        // No ring shrinking: stale ring-h values are never read by a pixel
        // that remains valid (1 ring per half-step, halo = 8 = #half-steps).
        updr[j] = img && (ry >= 1) && (ry < EXT-1) && (sx >= 1) && (sx < EXT-1);
        float v0=0.f,v1=0.f,w0=0.f,w1=0.f,w2=0.f,w3=0.f,a=0.f,c=0.f,d=0.f;
        if (img) {
            int gi = gyy*WW + gxx;
            v0 = u[pb + gi];   v1 = u[pb + HW + gi];
            w0 = p1[pb + gi];  w1 = p1[pb + HW + gi];
            w2 = p2[pb + gi];  w3 = p2[pb + HW + gi];
            a  = gxc[cb + gi]; c  = gyc[cb + gi];  d = rcc[cb + gi];
        }
        ru0[j]=v0; ru1[j]=v1; rp10[j]=w0; rp11[j]=w1; rp20[j]=w2; rp21[j]=w3;
        rgx[j]=a; rgy[j]=c; rrc[j]=d;
        su[ry][sx] = make_float4(v0, v1, 0.f, 0.f);
        sp[ry][sx] = make_float4(w0, w1, w2, w3);
    }
    __syncthreads();

    // Clamped window edges: taps of any upd pixel are in-bounds by
    // construction; clamped cells only feed dead (non-upd) computations.
    const int rT = (sy3 == 0) ? 0 : sy3 - 1;
    const int rB = (sy3 + RPS >= EXT) ? EXT-1 : sy3 + RPS;
    const int xm = (sx == 0) ? 0 : sx - 1;
    const int xp = (sx == EXT-1) ? EXT-1 : sx + 1;

    #pragma unroll
    for (int it = 0; it < FUSE; ++it) {
        // ---- u half-step: p window from LDS (12 b128), pointwise from regs ----
        {
            float4 Wm[RPS+2], Wc[RPS+2], Wp[RPS+2];    // W[i] = row sy3-1+i
            Wm[0] = sp[rT][xm];     Wc[0] = sp[rT][sx];   Wp[0] = sp[rT][xp];
            Wm[1] = sp[sy3  ][xm];                        Wp[1] = sp[sy3  ][xp];
            Wm[2] = sp[sy3+1][xm];                        Wp[2] = sp[sy3+1][xp];
            Wm[3] = sp[sy3+2][xm];                        Wp[3] = sp[sy3+2][xp];
            Wm[4] = sp[rB][xm];     Wc[4] = sp[rB][sx];   Wp[4] = sp[rB][xp];
            Wc[1] = make_float4(rp10[0], rp11[0], rp20[0], rp21[0]);
            Wc[2] = make_float4(rp10[1], rp11[1], rp20[1], rp21[1]);
            Wc[3] = make_float4(rp10[2], rp11[2], rp20[2], rp21[2]);
            #pragma unroll
            for (int j = 0; j < RPS; ++j) {
                if (updr[j]) {
                    // SBX over p1 (.x,.y): no center column
                    float x0 = (Wp[j].x-Wm[j].x) + 2.f*(Wp[j+1].x-Wm[j+1].x) + (Wp[j+2].x-Wm[j+2].x);
                    float x1 = (Wp[j].y-Wm[j].y) + 2.f*(Wp[j+1].y-Wm[j+1].y) + (Wp[j+2].y-Wm[j+2].y);
                    // SBY over p2 (.z,.w): no middle row
                    float y0 = (Wm[j+2].z-Wm[j].z) + 2.f*(Wc[j+2].z-Wc[j].z) + (Wp[j+2].z-Wp[j].z);
                    float y1 = (Wm[j+2].w-Wm[j].w) + 2.f*(Wc[j+2].w-Wc[j].w) + (Wp[j+2].w-Wp[j].w);

                    float g_x = rgx[j], g_y = rgy[j];
                    float ng  = g_x*g_x + g_y*g_y + EPSV;
                    float rho = rrc[j] + g_x*ru0[j] + g_y*ru1[j];
                    float th  = tl * ng;
                    float sgn = (rho > 0.f) ? 1.f : ((rho < 0.f) ? -1.f : 0.f);
                    float dd  = (fabsf(rho) < th) ? (rho / ng) : (tl * sgn);
                    ru0[j] = ru0[j] - dd*g_x + theta*(x0 + y0);
                    ru1[j] = ru1[j] - dd*g_y + theta*(x1 + y1);
                    su[sy3+j][sx] = make_float4(ru0[j], ru1[j], 0.f, 0.f);
                }
            }
        }
        __syncthreads();

        if (LAST && it == FUSE-1) break;    // 20th p-update never feeds the output

        // ---- p half-step: u window from LDS (12 b128), pointwise from regs ----
        {
            float4 Vm[RPS+2], Vc[RPS+2], Vp[RPS+2];
            Vm[0] = su[rT][xm];     Vc[0] = su[rT][sx];   Vp[0] = su[rT][xp];
            Vm[1] = su[sy3  ][xm];                        Vp[1] = su[sy3  ][xp];
            Vm[2] = su[sy3+1][xm];                        Vp[2] = su[sy3+1][xp];
            Vm[3] = su[sy3+2][xm];                        Vp[3] = su[sy3+2][xp];
            Vm[4] = su[rB][xm];     Vc[4] = su[rB][sx];   Vp[4] = su[rB][xp];
            Vc[1] = make_float4(ru0[0], ru1[0], 0.f, 0.f);
            Vc[2] = make_float4(ru0[1], ru1[1], 0.f, 0.f);
            Vc[3] = make_float4(ru0[2], ru1[2], 0.f, 0.f);
            #pragma unroll
            for (int j = 0; j < RPS; ++j) {
                if (updr[j]) {
                    float g1x = (Vp[j].x-Vm[j].x) + 2.f*(Vp[j+1].x-Vm[j+1].x) + (Vp[j+2].x-Vm[j+2].x);
                    float g1y = (Vm[j+2].x-Vm[j].x) + 2.f*(Vc[j+2].x-Vc[j].x) + (Vp[j+2].x-Vp[j].x);
                    float g2x = (Vp[j].y-Vm[j].y) + 2.f*(Vp[j+1].y-Vm[j+1].y) + (Vp[j+2].y-Vm[j+2].y);
                    float g2y = (Vm[j+2].y-Vm[j].y) + 2.f*(Vc[j+2].y-Vc[j].y) + (Vp[j+2].y-Vp[j].y);
                    float inv1 = 1.f / (1.f + r*(fabsf(g1x) + fabsf(g1y)));
                    float inv2 = 1.f / (1.f + r*(fabsf(g2x) + fabsf(g2y)));
                    rp10[j] = (rp10[j] + r*g1x) * inv1;
                    rp11[j] = (rp11[j] + r*g1y) * inv1;
                    rp20[j] = (rp20[j] + r*g2x) * inv2;
                    rp21[j] = (rp21[j] + r*g2y) * inv2;
                    sp[sy3+j][sx] = make_float4(rp10[j], rp11[j], rp20[j], rp21[j]);
                }
            }
        }
        __syncthreads();
    }

    // ---- write back interior straight from registers ----
    #pragma unroll
    for (int j = 0; j < RPS; ++j) {
        int ry = sy3 + j;
        if (updr[j] && ry >= HALO && ry < HALO+TILE && sx >= HALO && sx < HALO+TILE) {
            int go = (oy + ry)*WW + (ox + sx);
            u[pb + go]      = ru0[j];
            u[pb + HW + go] = ru1[j];
            if (!LAST) {
                p1[pb + go]      = rp10[j];
                p1[pb + HW + go] = rp11[j];
                p2[pb + go]      = rp20[j];
                p2[pb + HW + go] = rp21[j];
            }
        }
    }
}

extern "C" void kernel_launch(void* const* d_in, const int* in_sizes, int n_in,
                              void* d_out, int out_size, void* d_ws, size_t ws_size,
                              hipStream_t stream) {
    const float* xin = (const float*)d_in[0];
    const float* lam = (const float*)d_in[1];
    const float* tau = (const float*)d_in[2];
    const float* the = (const float*)d_in[3];
    float* u = (float*)d_out;              // u lives in d_out (B,2,H,W)

    float* ws = (float*)d_ws;
    float* p1 = ws;                        // B*2*HW
    float* p2 = ws + (size_t)BB*2*HW;      // B*2*HW
    float* gx = ws + (size_t)2*BB*2*HW;    // B*HW
    float* gy = gx + (size_t)BB*HW;        // B*HW
    float* rc = gy + (size_t)BB*HW;        // B*HW

    {
        dim3 blk(64, 4, 1);
        dim3 grd(WW/64, HH/4, BB);
        tvl1_init<<<grd, blk, 0, stream>>>(xin, u, p1, p2, gx, gy, rc);
    }

    dim3 blk(NTHR, 1, 1);
    dim3 grd(WW/TILE, HH/TILE, BB);        // 8 x 8 x 4 = 256 blocks = 1/CU
    const int NLAUNCH = N_ITER / FUSE;     // 5
    for (int j = 0; j < NLAUNCH; ++j) {
        if (j < NLAUNCH - 1)
            tvl1_fused<0><<<grd, blk, 0, stream>>>(u, p1, p2, gx, gy, rc, lam, tau, the);
        else
            tvl1_fused<1><<<grd, blk, 0, stream>>>(u, p1, p2, gx, gy, rc, lam, tau, the);
    }
}

// Round 13
// 91.155 us; speedup vs baseline: 1.1607x; 1.0904x over previous
//
#include <hip/hip_runtime.h>

#define HH 256
#define WW 256
#define BB 4
#define HW (HH*WW)
#define N_ITER 20
#define EPSV 1e-8f

#define FUSE 4
#define TILE 32
#define HALO (2*FUSE)            // 8
#define EXT  (TILE + 2*HALO)     // 48
#define EPAD 49                  // odd row stride in float4 cells
#define NTHR 768                 // 16 strips of 3 rows x 48 cols
#define RPS  3                   // rows per strip

__device__ __forceinline__ float ldz(const float* __restrict__ p, int y, int x) {
    if ((unsigned)y < HH && (unsigned)x < WW) return p[y*WW + x];
    return 0.0f;
}

template<int FIRST, int LAST>
__global__ __launch_bounds__(NTHR)
void tvl1_fused(const float* __restrict__ xin,
                float* __restrict__ u,
                float* __restrict__ p1, float* __restrict__ p2,
                float* __restrict__ gxc, float* __restrict__ gyc,
                float* __restrict__ rcc,
                const float* __restrict__ lam, const float* __restrict__ tau,
                const float* __restrict__ the) {
    // All-b128 LDS (b64 empirically unsafe: R6/R10).
    // sp cell = (p1c0,p1c1,p2c0,p2c1); su cell = (u0,u1,0,0).
    // Each thread owns a 3-row column strip: own-column cells in regs;
    // one 5-row x 3-col window (12 b128 reads) serves all 3 pixels per phase.
    __shared__ float4 su[EXT][EPAD];
    __shared__ float4 sp[EXT][EPAD];     // 2 * 48*49*16B = 75.3 KB

    const int tid = threadIdx.x;
    const int sx  = tid % EXT;               // column 0..47 (const divisor)
    const int sy3 = (tid / EXT) * RPS;       // strip top row: 0,3,...,45
    const int b  = blockIdx.z;
    const int ox = blockIdx.x*TILE - HALO;
    const int oy = blockIdx.y*TILE - HALO;
    const int pb = b*2*HW, cb = b*HW;
    const float theta = the[0];
    const float tl = theta * lam[0];
    const float r = tau[0] / theta;

    const int gxx = ox + sx;
    const bool inx = ((unsigned)gxx < WW);

    float ru0[RPS], ru1[RPS], rp10[RPS], rp11[RPS], rp20[RPS], rp21[RPS];
    float rgx[RPS], rgy[RPS], rrc[RPS];
    bool updr[RPS];

    // Clamped window edges: taps of any upd pixel are in-bounds by
    // construction; clamped cells only feed dead (non-upd) computations.
    const int rT = (sy3 == 0) ? 0 : sy3 - 1;
    const int rB = (sy3 + RPS >= EXT) ? EXT-1 : sy3 + RPS;
    const int xm = (sx == 0) ? 0 : sx - 1;
    const int xp = (sx == EXT-1) ? EXT-1 : sx + 1;

    #pragma unroll
    for (int j = 0; j < RPS; ++j) {
        int ry = sy3 + j;
        int gyy = oy + ry;
        bool img = inx && ((unsigned)gyy < HH);
        // update set: in-image (SAME-pad zeros stay zero) + stencil-readable.
        // No ring shrinking: stale ring-h values are never read by a pixel
        // that remains valid (1 ring per half-step, halo = 8 = #half-steps).
        updr[j] = img && (ry >= 1) && (ry < EXT-1) && (sx >= 1) && (sx < EXT-1);
    }

    if (FIRST) {
        // ---- stage (im1, im0) into su; compute gx/gy/rc; u=p=0 ----
        float im1r[RPS], im0r[RPS];
        #pragma unroll
        for (int j = 0; j < RPS; ++j) {
            int gyy = oy + sy3 + j;
            im1r[j] = ldz(xin + pb + HW, gyy, gxx);
            im0r[j] = ldz(xin + pb,      gyy, gxx);
            su[sy3 + j][sx] = make_float4(im1r[j], im0r[j], 0.f, 0.f);
        }
        __syncthreads();
        {
            float4 Vm[RPS+2], Vc[RPS+2], Vp[RPS+2];   // V[i] = row sy3-1+i
            Vm[0] = su[rT][xm];     Vc[0] = su[rT][sx];   Vp[0] = su[rT][xp];
            Vm[1] = su[sy3  ][xm];                        Vp[1] = su[sy3  ][xp];
            Vm[2] = su[sy3+1][xm];                        Vp[2] = su[sy3+1][xp];
            Vm[3] = su[sy3+2][xm];                        Vp[3] = su[sy3+2][xp];
            Vm[4] = su[rB][xm];     Vc[4] = su[rB][sx];   Vp[4] = su[rB][xp];
            Vc[1] = make_float4(im1r[0], im0r[0], 0.f, 0.f);
            Vc[2] = make_float4(im1r[1], im0r[1], 0.f, 0.f);
            Vc[3] = make_float4(im1r[2], im0r[2], 0.f, 0.f);
            #pragma unroll
            for (int j = 0; j < RPS; ++j) {
                // sobel of im1 (.x): SX has no center column, SY no middle row
                rgx[j] = (Vp[j].x-Vm[j].x) + 2.f*(Vp[j+1].x-Vm[j+1].x) + (Vp[j+2].x-Vm[j+2].x);
                rgy[j] = (Vm[j+2].x-Vm[j].x) + 2.f*(Vc[j+2].x-Vc[j].x) + (Vp[j+2].x-Vp[j].x);
                rrc[j] = im1r[j] - im0r[j];
                ru0[j]=0.f; ru1[j]=0.f;
                rp10[j]=0.f; rp11[j]=0.f; rp20[j]=0.f; rp21[j]=0.f;
                // persist gx/gy/rc for kernels 2..5 (interior cells exactly
                // partition the image across blocks)
                int ry = sy3 + j;
                if (ry >= HALO && ry < HALO+TILE && sx >= HALO && sx < HALO+TILE) {
                    int gi = (oy + ry)*WW + gxx;
                    gxc[cb + gi] = rgx[j];
                    gyc[cb + gi] = rgy[j];
                    rcc[cb + gi] = rrc[j];
                }
            }
        }
        __syncthreads();    // all windows read before su is repurposed
        #pragma unroll
        for (int j = 0; j < RPS; ++j) {
            su[sy3 + j][sx] = make_float4(0.f, 0.f, 0.f, 0.f);
            sp[sy3 + j][sx] = make_float4(0.f, 0.f, 0.f, 0.f);
        }
        __syncthreads();
    } else {
        // ---- stage: regs hold strip state; LDS gets neighbor-visible copies ----
        #pragma unroll
        for (int j = 0; j < RPS; ++j) {
            int ry = sy3 + j;
            int gyy = oy + ry;
            bool img = inx && ((unsigned)gyy < HH);
            float v0=0.f,v1=0.f,w0=0.f,w1=0.f,w2=0.f,w3=0.f,a=0.f,c=0.f,d=0.f;
            if (img) {
                int gi = gyy*WW + gxx;
                v0 = u[pb + gi];   v1 = u[pb + HW + gi];
                w0 = p1[pb + gi];  w1 = p1[pb + HW + gi];
                w2 = p2[pb + gi];  w3 = p2[pb + HW + gi];
                a  = gxc[cb + gi]; c  = gyc[cb + gi];  d = rcc[cb + gi];
            }
            ru0[j]=v0; ru1[j]=v1; rp10[j]=w0; rp11[j]=w1; rp20[j]=w2; rp21[j]=w3;
            rgx[j]=a; rgy[j]=c; rrc[j]=d;
            su[ry][sx] = make_float4(v0, v1, 0.f, 0.f);
            sp[ry][sx] = make_float4(w0, w1, w2, w3);
        }
        __syncthreads();
    }

    #pragma unroll
    for (int it = 0; it < FUSE; ++it) {
        // ---- u half-step: p window from LDS (12 b128), pointwise from regs ----
        {
            float4 Wm[RPS+2], Wc[RPS+2], Wp[RPS+2];    // W[i] = row sy3-1+i
            Wm[0] = sp[rT][xm];     Wc[0] = sp[rT][sx];   Wp[0] = sp[rT][xp];
            Wm[1] = sp[sy3  ][xm];                        Wp[1] = sp[sy3  ][xp];
            Wm[2] = sp[sy3+1][xm];                        Wp[2] = sp[sy3+1][xp];
            Wm[3] = sp[sy3+2][xm];                        Wp[3] = sp[sy3+2][xp];
            Wm[4] = sp[rB][xm];     Wc[4] = sp[rB][sx];   Wp[4] = sp[rB][xp];
            Wc[1] = make_float4(rp10[0], rp11[0], rp20[0], rp21[0]);
            Wc[2] = make_float4(rp10[1], rp11[1], rp20[1], rp21[1]);
            Wc[3] = make_float4(rp10[2], rp11[2], rp20[2], rp21[2]);
            #pragma unroll
            for (int j = 0; j < RPS; ++j) {
                if (updr[j]) {
                    // SBX over p1 (.x,.y): no center column
                    float x0 = (Wp[j].x-Wm[j].x) + 2.f*(Wp[j+1].x-Wm[j+1].x) + (Wp[j+2].x-Wm[j+2].x);
                    float x1 = (Wp[j].y-Wm[j].y) + 2.f*(Wp[j+1].y-Wm[j+1].y) + (Wp[j+2].y-Wm[j+2].y);
                    // SBY over p2 (.z,.w): no middle row
                    float y0 = (Wm[j+2].z-Wm[j].z) + 2.f*(Wc[j+2].z-Wc[j].z) + (Wp[j+2].z-Wp[j].z);
                    float y1 = (Wm[j+2].w-Wm[j].w) + 2.f*(Wc[j+2].w-Wc[j].w) + (Wp[j+2].w-Wp[j].w);

                    float g_x = rgx[j], g_y = rgy[j];
                    float ng  = g_x*g_x + g_y*g_y + EPSV;
                    float rho = rrc[j] + g_x*ru0[j] + g_y*ru1[j];
                    float th  = tl * ng;
                    float sgn = (rho > 0.f) ? 1.f : ((rho < 0.f) ? -1.f : 0.f);
                    float dd  = (fabsf(rho) < th) ? (rho / ng) : (tl * sgn);
                    ru0[j] = ru0[j] - dd*g_x + theta*(x0 + y0);
                    ru1[j] = ru1[j] - dd*g_y + theta*(x1 + y1);
                    su[sy3+j][sx] = make_float4(ru0[j], ru1[j], 0.f, 0.f);
                }
            }
        }
        __syncthreads();

        if (LAST && it == FUSE-1) break;    // 20th p-update never feeds the output

        // ---- p half-step: u window from LDS (12 b128), pointwise from regs ----
        {
            float4 Vm[RPS+2], Vc[RPS+2], Vp[RPS+2];
            Vm[0] = su[rT][xm];     Vc[0] = su[rT][sx];   Vp[0] = su[rT][xp];
            Vm[1] = su[sy3  ][xm];                        Vp[1] = su[sy3  ][xp];
            Vm[2] = su[sy3+1][xm];                        Vp[2] = su[sy3+1][xp];
            Vm[3] = su[sy3+2][xm];                        Vp[3] = su[sy3+2][xp];
            Vm[4] = su[rB][xm];     Vc[4] = su[rB][sx];   Vp[4] = su[rB][xp];
            Vc[1] = make_float4(ru0[0], ru1[0], 0.f, 0.f);
            Vc[2] = make_float4(ru0[1], ru1[1], 0.f, 0.f);
            Vc[3] = make_float4(ru0[2], ru1[2], 0.f, 0.f);
            #pragma unroll
            for (int j = 0; j < RPS; ++j) {
                if (updr[j]) {
                    float g1x = (Vp[j].x-Vm[j].x) + 2.f*(Vp[j+1].x-Vm[j+1].x) + (Vp[j+2].x-Vm[j+2].x);
                    float g1y = (Vm[j+2].x-Vm[j].x) + 2.f*(Vc[j+2].x-Vc[j].x) + (Vp[j+2].x-Vp[j].x);
                    float g2x = (Vp[j].y-Vm[j].y) + 2.f*(Vp[j+1].y-Vm[j+1].y) + (Vp[j+2].y-Vm[j+2].y);
                    float g2y = (Vm[j+2].y-Vm[j].y) + 2.f*(Vc[j+2].y-Vc[j].y) + (Vp[j+2].y-Vp[j].y);
                    float inv1 = 1.f / (1.f + r*(fabsf(g1x) + fabsf(g1y)));
                    float inv2 = 1.f / (1.f + r*(fabsf(g2x) + fabsf(g2y)));
                    rp10[j] = (rp10[j] + r*g1x) * inv1;
                    rp11[j] = (rp11[j] + r*g1y) * inv1;
                    rp20[j] = (rp20[j] + r*g2x) * inv2;
                    rp21[j] = (rp21[j] + r*g2y) * inv2;
                    sp[sy3+j][sx] = make_float4(rp10[j], rp11[j], rp20[j], rp21[j]);
                }
            }
        }
        __syncthreads();
    }

    // ---- write back interior straight from registers ----
    #pragma unroll
    for (int j = 0; j < RPS; ++j) {
        int ry = sy3 + j;
        if (updr[j] && ry >= HALO && ry < HALO+TILE && sx >= HALO && sx < HALO+TILE) {
            int go = (oy + ry)*WW + (ox + sx);
            u[pb + go]      = ru0[j];
            u[pb + HW + go] = ru1[j];
            if (!LAST) {
                p1[pb + go]      = rp10[j];
                p1[pb + HW + go] = rp11[j];
                p2[pb + go]      = rp20[j];
                p2[pb + HW + go] = rp21[j];
            }
        }
    }
}

extern "C" void kernel_launch(void* const* d_in, const int* in_sizes, int n_in,
                              void* d_out, int out_size, void* d_ws, size_t ws_size,
                              hipStream_t stream) {
    const float* xin = (const float*)d_in[0];
    const float* lam = (const float*)d_in[1];
    const float* tau = (const float*)d_in[2];
    const float* the = (const float*)d_in[3];
    float* u = (float*)d_out;              // u lives in d_out (B,2,H,W)

    float* ws = (float*)d_ws;
    float* p1 = ws;                        // B*2*HW
    float* p2 = ws + (size_t)BB*2*HW;      // B*2*HW
    float* gx = ws + (size_t)2*BB*2*HW;    // B*HW
    float* gy = gx + (size_t)BB*HW;        // B*HW
    float* rc = gy + (size_t)BB*HW;        // B*HW

    dim3 blk(NTHR, 1, 1);
    dim3 grd(WW/TILE, HH/TILE, BB);        // 8 x 8 x 4 = 256 blocks = 1/CU
    // 5 dispatches total: init merged into kernel 1 (FIRST computes gx/gy/rc
    // in-LDS and starts from u=p=0, skipping all state staging loads).
    tvl1_fused<1,0><<<grd, blk, 0, stream>>>(xin, u, p1, p2, gx, gy, rc, lam, tau, the);
    tvl1_fused<0,0><<<grd, blk, 0, stream>>>(xin, u, p1, p2, gx, gy, rc, lam, tau, the);
    tvl1_fused<0,0><<<grd, blk, 0, stream>>>(xin, u, p1, p2, gx, gy, rc, lam, tau, the);
    tvl1_fused<0,0><<<grd, blk, 0, stream>>>(xin, u, p1, p2, gx, gy, rc, lam, tau, the);
    tvl1_fused<0,1><<<grd, blk, 0, stream>>>(xin, u, p1, p2, gx, gy, rc, lam, tau, the);
}